// Round 4
// baseline (5051.460 us; speedup 1.0000x reference)
//
#include <hip/hip_runtime.h>
#include <hip/hip_bf16.h>
#include <stdint.h>

typedef __bf16 bf16_t;
typedef __bf16 bf16x8 __attribute__((ext_vector_type(8)));
typedef float  f32x4  __attribute__((ext_vector_type(4)));

#define HP 514   // padded spatial width (512 + 2)

__device__ __forceinline__ bf16_t f2bf(float f) { return (bf16_t)f; }

// ---------- L0: 1->64 1x1 conv + PReLU; fp32 NCHW -> padded NHWC bf16 ----------
__global__ void l0_kernel(const float* __restrict__ A, const float* __restrict__ w0,
                          const float* __restrict__ b0, const float* __restrict__ p0,
                          bf16_t* __restrict__ X0)
{
    int idx = blockIdx.x * 256 + threadIdx.x;
    if (idx >= HP * HP * 64) return;
    int c   = idx & 63;
    int pix = idx >> 6;
    int py = pix / HP, px = pix - py * HP;
    float v = 0.f;
    if (py >= 1 && py <= 512 && px >= 1 && px <= 512) {
        float a = A[(py - 1) * 512 + (px - 1)];
        v = fmaf(w0[c], a, b0[c]);
        v = v >= 0.f ? v : p0[0] * v;
    }
    X0[idx] = f2bf(v);
}

// ---------- zero full rows [r0, r0+n) of a strip buffer ----------
__global__ void zero_rows_kernel(bf16_t* __restrict__ buf, int C, int r0, int n)
{
    int idx = blockIdx.x * 256 + threadIdx.x;
    int rowsz = HP * C;
    if (idx >= n * rowsz) return;
    int r = idx / rowsz, j = idx - r * rowsz;
    buf[(size_t)(r0 + r) * rowsz + j] = f2bf(0.f);
}

// ---------- zero cols 0 and 513 for rows [0, R) ----------
__global__ void zero_cols_kernel(bf16_t* __restrict__ buf, int C, int R)
{
    int idx = blockIdx.x * 256 + threadIdx.x;
    if (idx >= R * 2 * C) return;
    int r = idx / (2 * C);
    int t = idx - r * 2 * C;
    int col = (t < C) ? 0 : 513;
    int c = t % C;
    buf[((size_t)r * HP + col) * C + c] = f2bf(0.f);
}

// ---------- weight transform: OIHW fp32 -> MFMA-fragment-ordered bf16 ----------
// wt[(((ci*9 + tap)*G + gabs)*64 + l)*8 + j] = w[(cout*CIN+cin)*9 + tap]
//   cout = gabs*16 + (l&15), cin = ci*32 + (l>>4)*8 + j, G = COUT/16
__global__ void wtrans_kernel(const float* __restrict__ w, bf16_t* __restrict__ wt,
                              int COUT, int CIN)
{
    int idx = blockIdx.x * 256 + threadIdx.x;
    if (idx >= COUT * CIN * 9) return;
    int G    = COUT / 16;
    int j    = idx & 7;
    int l    = (idx >> 3) & 63;
    int t    = idx >> 9;
    int gabs = t % G;
    int t2   = t / G;
    int tap  = t2 % 9;
    int ci   = t2 / 9;
    int cout = gabs * 16 + (l & 15);
    int cin  = ci * 32 + (l >> 4) * 8 + j;
    wt[idx] = f2bf(w[(cout * CIN + cin) * 9 + tap]);
}

// ---------- 3x3 conv + bias + PReLU, implicit GEMM, bf16 MFMA ----------
// Block: 256 thr, tile 256 px (16y x 16x) x BN couts.
// Wave tile: 8 rows x (BN/2) couts -> 8 m-frags x GW B-frags, 32 MFMA/tap/wave.
// A: LDS [18r][4q][20px][8c] double-buffered (reg-staged, conflict-free reads).
// B: LDS fragment-ordered, 2-tap phase double buffer via global_load_lds.
// 5 barriers per 32-channel chunk (~308 compute-cycles each).
template<int CIN, int COUT, int BN>
__global__ __launch_bounds__(256, 2)
void conv3x3_kernel(const bf16_t* __restrict__ in, const bf16_t* __restrict__ wt,
                    const float* __restrict__ bias, const float* __restrict__ alpha,
                    bf16_t* __restrict__ out,
                    int n_rows, int in_off, int in_alloc, int out_off)
{
    constexpr int G     = COUT / 16;     // global cout groups (wt layout)
    constexpr int GPB   = BN / 16;       // cout groups per block
    constexpr int GW    = BN / 32;       // cout groups per wave (n-half)
    constexpr int NC    = CIN / 32;      // channel chunks
    constexpr int ASLAB = 18 * 4 * 20 * 8;   // 11520 elems per A buffer
    constexpr int BTAP  = BN * 32;           // elems per B tap tile
    constexpr int BSZ2  = 2 * BTAP;          // elems per B phase buffer (2 taps)
    __shared__ __align__(16) bf16_t As[2 * ASLAB];
    __shared__ __align__(16) bf16_t Bs[2 * BSZ2];

    const int tid  = threadIdx.x;
    const int lane = tid & 63;
    const int wave = tid >> 6;
    const int lm   = lane & 15;
    const int quad = lane >> 4;
    const int wave_m = wave >> 1;
    const int wave_n = wave & 1;

    const int x0g = blockIdx.x * 16;     // input col base (padded coords)
    const int y0  = blockIdx.y * 16;     // local out row base
    const int zb  = blockIdx.z;
    const int gb_blk = zb * GPB;

    // ---- A staging: 1296 16B-units (18r x 18px x 4q); 5 full passes + tail ----
    int soff[6], sdst[6];
    #pragma unroll
    for (int i = 0; i < 6; ++i) {
        int u = i * 256 + tid;
        int uu = u < 1296 ? u : 0;
        int r   = uu / 72;
        int rem = uu - r * 72;
        int px = rem >> 2, q = rem & 3;
        int grow = in_off + y0 + r;
        grow = grow < 0 ? 0 : (grow >= in_alloc ? in_alloc - 1 : grow);
        soff[i] = (grow * HP + x0g + px) * CIN + q * 8;
        sdst[i] = ((r * 4 + q) * 20 + px) * 8;
    }
    const bool tail_ok = (tid < 16);     // pass 5 covers units 1280..1295

    // ---- B staging via global_load_lds: wave w, pass p stages unit (p*4+w) ----
    auto stageB = [&](int ci9t, int ntaps, int dstbuf) {
        #pragma unroll
        for (int p = 0; p < GPB / 2; ++p) {
            int idx = p * 4 + wave;
            int ti  = idx / GPB;
            int g   = idx % GPB;
            if (ti < ntaps) {
                const bf16_t* src = wt + ((size_t)(ci9t + ti) * G + gb_blk + g) * 512 + lane * 8;
                bf16_t* dst = Bs + dstbuf * BSZ2 + (ti * GPB + g) * 512;
                __builtin_amdgcn_global_load_lds(
                    (__attribute__((address_space(1))) void*)src,
                    (__attribute__((address_space(3))) void*)dst, 16, 0, 0);
            }
        }
    };

    f32x4 acc[8][GW] = {};
    int ab = 0, buf = 0;

    auto comp = [&](int tap, int ti, int bbuf) {
        const int dy = tap / 3, dx = tap - dy * 3;
        bf16x8 bfr[GW];
        #pragma unroll
        for (int g = 0; g < GW; ++g)
            bfr[g] = *(const bf16x8*)(Bs + bbuf * BSZ2 + (ti * GPB + wave_n * GW + g) * 512 + lane * 8);
        #pragma unroll
        for (int h = 0; h < 2; ++h) {
            bf16x8 a[4];
            #pragma unroll
            for (int mt = 0; mt < 4; ++mt) {
                int r = wave_m * 8 + h * 4 + mt + dy;
                a[mt] = *(const bf16x8*)(As + ab * ASLAB + ((r * 4 + quad) * 20 + dx + lm) * 8);
            }
            #pragma unroll
            for (int mt = 0; mt < 4; ++mt)
                #pragma unroll
                for (int g = 0; g < GW; ++g)
                    acc[h * 4 + mt][g] = __builtin_amdgcn_mfma_f32_16x16x32_bf16(
                        a[mt], bfr[g], acc[h * 4 + mt][g], 0, 0, 0);
        }
    };

    // ---- prologue: A chunk0 (regs -> LDS), B taps {0,1} -> buf 0 ----
    {
        bf16x8 s[6];
        #pragma unroll
        for (int i = 0; i < 5; ++i) s[i] = *(const bf16x8*)(in + soff[i]);
        if (tail_ok) s[5] = *(const bf16x8*)(in + soff[5]);
        #pragma unroll
        for (int i = 0; i < 5; ++i) *(bf16x8*)(As + sdst[i]) = s[i];
        if (tail_ok) *(bf16x8*)(As + sdst[5]) = s[5];
    }
    stageB(0, 2, 0);
    __syncthreads();

    #pragma unroll 1
    for (int ci = 0; ci < NC; ++ci) {
        const bool more = (ci + 1 < NC);
        bf16x8 sreg[6];
        #pragma unroll
        for (int ph = 0; ph < 5; ++ph) {
            // prefetch next phase's B tile(s)
            if (ph <= 2)          stageB(ci * 9 + 2 * ph + 2, 2, buf ^ 1);
            else if (ph == 3)     stageB(ci * 9 + 8, 1, buf ^ 1);
            else if (more)        stageB((ci + 1) * 9, 2, buf ^ 1);
            // A chunk+1 global loads issued after phase-0 barrier
            if (ph == 1 && more) {
                const int cc = (ci + 1) * 32;
                #pragma unroll
                for (int i = 0; i < 5; ++i) sreg[i] = *(const bf16x8*)(in + soff[i] + cc);
                if (tail_ok) sreg[5] = *(const bf16x8*)(in + soff[5] + cc);
            }
            comp(2 * ph, 0, buf);
            if (ph < 4) comp(2 * ph + 1, 1, buf);
            if (ph == 4 && more) {
                bf16_t* dstb = As + (ab ^ 1) * ASLAB;
                #pragma unroll
                for (int i = 0; i < 5; ++i) *(bf16x8*)(dstb + sdst[i]) = sreg[i];
                if (tail_ok) *(bf16x8*)(dstb + sdst[5]) = sreg[5];
            }
            __syncthreads();
            buf ^= 1;
        }
        ab ^= 1;
    }

    // ---- epilogue: bias + PReLU, bf16 NHWC store ----
    const float al = alpha[0];
    #pragma unroll
    for (int g = 0; g < GW; ++g) {
        const int n = zb * BN + wave_n * (BN / 2) + g * 16 + lm;
        const float bv = bias[n];
        #pragma unroll
        for (int mt = 0; mt < 8; ++mt) {
            int ly = y0 + wave_m * 8 + mt;
            if (ly < n_rows) {
                f32x4 v = acc[mt][g];
                #pragma unroll
                for (int r = 0; r < 4; ++r) {
                    int x = x0g + quad * 4 + r + 1;
                    float f = v[r] + bv;
                    f = f >= 0.f ? f : al * f;
                    out[((size_t)(out_off + ly) * HP + x) * COUT + n] = f2bf(f);
                }
            }
        }
    }
}

// ---------- L5 (64->1, k3) + bias + PReLU per strip, fp32 T out ----------
__device__ __forceinline__ float conv64_at(const bf16_t* __restrict__ X,
                                           const float* __restrict__ wsh,
                                           int y, int x, float bv)
{
    float acc = bv;
    #pragma unroll
    for (int dy = 0; dy < 3; ++dy) {
        #pragma unroll
        for (int dx = 0; dx < 3; ++dx) {
            const bf16x8* p = (const bf16x8*)(X + ((size_t)(y + dy) * HP + (x + dx)) * 64);
            const float* wf = wsh + (dy * 3 + dx) * 64;
            #pragma unroll
            for (int j = 0; j < 8; ++j) {
                bf16x8 v = p[j];
                #pragma unroll
                for (int k = 0; k < 8; ++k)
                    acc = fmaf((float)v[k], wf[j * 8 + k], acc);
            }
        }
    }
    return acc;
}

__global__ __launch_bounds__(256)
void l5_strip_kernel(const bf16_t* __restrict__ B4, const bf16_t* __restrict__ wt5,
                     const float* __restrict__ b5, const float* __restrict__ p5,
                     float* __restrict__ T, int abs_row0)
{
    __shared__ float wsh[9 * 64];
    for (int i = threadIdx.x; i < 576; i += 256) wsh[i] = (float)wt5[i];
    __syncthreads();
    int idx = blockIdx.x * 256 + threadIdx.x;
    int ly = idx >> 9, x = idx & 511;
    float bv = b5[0], al = p5[0];
    float t = conv64_at(B4, wsh, ly, x, bv);
    t = t >= 0.f ? t : al * t;
    T[(size_t)(abs_row0 + ly) * 512 + x] = t;
}

// ---------- weight transform for L5 (plain [tap][cin], tiny) ----------
__global__ void wtrans5_kernel(const float* __restrict__ w, bf16_t* __restrict__ wt)
{
    int idx = blockIdx.x * 256 + threadIdx.x;
    if (idx >= 9 * 64) return;
    int cin = idx % 64, tap = idx / 64;
    wt[idx] = f2bf(w[cin * 9 + tap]);
}

// ---------- final symmetrize ----------
__global__ __launch_bounds__(256)
void sym_kernel(const float* __restrict__ T, float* __restrict__ out)
{
    int idx = blockIdx.x * 256 + threadIdx.x;
    int y = idx >> 9, x = idx & 511;
    out[idx] = 0.5f * (T[idx] + T[x * 512 + y]);
}

// ----------------------------------------------------------------------------
extern "C" void kernel_launch(void* const* d_in, const int* in_sizes, int n_in,
                              void* d_out, int out_size, void* d_ws, size_t ws_size,
                              hipStream_t stream)
{
    const float* A = (const float*)d_in[0];
    const float *w[6], *b[6], *p[6];
    for (int i = 0; i < 6; ++i) {
        w[i] = (const float*)d_in[1 + 3 * i];
        b[i] = (const float*)d_in[2 + 3 * i];
        p[i] = (const float*)d_in[3 + 3 * i];
    }

    auto footprint = [](long long S) -> size_t {
        auto al = [](size_t v) { return (v + 255) & ~(size_t)255; };
        size_t t = 0;
        t += al((size_t)HP * HP * 64 * 2);
        t += al((size_t)(S + 8) * HP * 256 * 2);
        t += al((size_t)(S + 6) * HP * 512 * 2);
        t += al((size_t)(S + 2) * HP * 64 * 2);
        t += al((size_t)512 * 512 * 4);
        t += al((size_t)9 * 256 * 64 * 2);
        t += al((size_t)9 * 512 * 256 * 2);
        t += al((size_t)9 * 256 * 512 * 2);
        t += al((size_t)9 * 64 * 256 * 2);
        t += al((size_t)9 * 64 * 2);
        return t;
    };
    const int cand[6] = {512, 256, 128, 64, 32, 16};
    int S = 16;
    for (int i = 0; i < 6; ++i)
        if (footprint(cand[i]) <= ws_size) { S = cand[i]; break; }
    const int nStrips = 512 / S;

    char* ws = (char*)d_ws;
    size_t off = 0;
    auto carve = [&](size_t bytes) -> void* {
        void* r = ws + off;
        off += (bytes + 255) & ~(size_t)255;
        return r;
    };
    bf16_t* X0  = (bf16_t*)carve((size_t)HP * HP * 64 * 2);
    bf16_t* B1  = (bf16_t*)carve((size_t)(S + 8) * HP * 256 * 2);
    bf16_t* B2  = (bf16_t*)carve((size_t)(S + 6) * HP * 512 * 2);
    bf16_t* B4  = (bf16_t*)carve((size_t)(S + 2) * HP * 64 * 2);
    float*  T   = (float*)carve((size_t)512 * 512 * 4);
    bf16_t* wt1 = (bf16_t*)carve((size_t)9 * 256 * 64 * 2);
    bf16_t* wt2 = (bf16_t*)carve((size_t)9 * 512 * 256 * 2);
    bf16_t* wt3 = (bf16_t*)carve((size_t)9 * 256 * 512 * 2);
    bf16_t* wt4 = (bf16_t*)carve((size_t)9 * 64 * 256 * 2);
    bf16_t* wt5 = (bf16_t*)carve((size_t)9 * 64 * 2);
    bf16_t* B3  = B1;   // alias: B1 dead after each strip's L2

    auto cdiv = [](int a, int bq) { return (a + bq - 1) / bq; };
    auto zrows = [&](bf16_t* buf, int C, int r0, int n) {
        if (n > 0)
            zero_rows_kernel<<<cdiv(n * HP * C, 256), 256, 0, stream>>>(buf, C, r0, n);
    };

    wtrans_kernel<<<cdiv(9 * 256 * 64, 256), 256, 0, stream>>>(w[1], wt1, 256, 64);
    wtrans_kernel<<<cdiv(9 * 512 * 256, 256), 256, 0, stream>>>(w[2], wt2, 512, 256);
    wtrans_kernel<<<cdiv(9 * 256 * 512, 256), 256, 0, stream>>>(w[3], wt3, 256, 512);
    wtrans_kernel<<<cdiv(9 * 64 * 256, 256), 256, 0, stream>>>(w[4], wt4, 64, 256);
    wtrans5_kernel<<<cdiv(9 * 64, 256), 256, 0, stream>>>(w[5], wt5);
    l0_kernel<<<cdiv(HP * HP * 64, 256), 256, 0, stream>>>(A, w[0], b[0], p[0], X0);
    zero_cols_kernel<<<cdiv((S + 8) * 2 * 256, 256), 256, 0, stream>>>(B1, 256, S + 8);
    zero_cols_kernel<<<cdiv((S + 6) * 2 * 512, 256), 256, 0, stream>>>(B2, 512, S + 6);
    zero_cols_kernel<<<cdiv((S + 2) * 2 * 64, 256), 256, 0, stream>>>(B4, 64, S + 2);

    for (int s = 0; s < nStrips; ++s) {
        const int base = S * s;
        int o0[5], nn[5], ooff[5], alloc[5];
        for (int k = 1; k <= 4; ++k) {
            int hk = 5 - k;                      // halos 4,3,2,1
            int a0 = base - hk, a1 = base + S + hk;
            int c0 = a0 < 0 ? 0 : a0, c1 = a1 > 512 ? 512 : a1;
            o0[k] = c0; nn[k] = c1 - c0; ooff[k] = c0 - a0; alloc[k] = S + 2 * hk;
        }
        // L1: X0 -> B1
        {
            int in_off = o0[1];
            dim3 g(32, cdiv(nn[1], 16), 2);
            conv3x3_kernel<64, 256, 128><<<g, 256, 0, stream>>>(
                X0, wt1, b[1], p[1], B1, nn[1], in_off, 514, ooff[1]);
            zrows(B1, 256, 0, ooff[1]);
            zrows(B1, 256, ooff[1] + nn[1], alloc[1] - ooff[1] - nn[1]);
        }
        // L2: B1 -> B2
        {
            int in_off = (o0[2] - 1) - (base - 4);
            dim3 g(32, cdiv(nn[2], 16), 4);
            conv3x3_kernel<256, 512, 128><<<g, 256, 0, stream>>>(
                B1, wt2, b[2], p[2], B2, nn[2], in_off, alloc[1], ooff[2]);
            zrows(B2, 512, 0, ooff[2]);
            zrows(B2, 512, ooff[2] + nn[2], alloc[2] - ooff[2] - nn[2]);
        }
        // L3: B2 -> B3
        {
            int in_off = (o0[3] - 1) - (base - 3);
            dim3 g(32, cdiv(nn[3], 16), 2);
            conv3x3_kernel<512, 256, 128><<<g, 256, 0, stream>>>(
                B2, wt3, b[3], p[3], B3, nn[3], in_off, alloc[2], ooff[3]);
            zrows(B3, 256, 0, ooff[3]);
            zrows(B3, 256, ooff[3] + nn[3], alloc[3] - ooff[3] - nn[3]);
        }
        // L4: B3 -> B4
        {
            int in_off = (o0[4] - 1) - (base - 2);
            dim3 g(32, cdiv(nn[4], 16), 1);
            conv3x3_kernel<256, 64, 64><<<g, 256, 0, stream>>>(
                B3, wt4, b[4], p[4], B4, nn[4], in_off, alloc[3], ooff[4]);
            zrows(B4, 64, 0, ooff[4]);
            zrows(B4, 64, ooff[4] + nn[4], alloc[4] - ooff[4] - nn[4]);
        }
        // L5
        l5_strip_kernel<<<(S * 512) / 256, 256, 0, stream>>>(B4, wt5, b[5], p[5], T, base);
    }

    sym_kernel<<<(512 * 512) / 256, 256, 0, stream>>>(T, (float*)d_out);
}

// Round 5
// 1679.890 us; speedup vs baseline: 3.0070x; 3.0070x over previous
//
#include <hip/hip_runtime.h>
#include <hip/hip_bf16.h>
#include <stdint.h>

typedef __bf16 bf16_t;
typedef __bf16 bf16x8 __attribute__((ext_vector_type(8)));
typedef float  f32x4  __attribute__((ext_vector_type(4)));

#define HP 514   // padded spatial width (512 + 2)
#define AS1 __attribute__((address_space(1)))
#define AS3 __attribute__((address_space(3)))

__device__ __forceinline__ bf16_t f2bf(float f) { return (bf16_t)f; }

// ---------- L0: 1->64 1x1 conv + PReLU; fp32 NCHW -> padded NHWC bf16 ----------
__global__ void l0_kernel(const float* __restrict__ A, const float* __restrict__ w0,
                          const float* __restrict__ b0, const float* __restrict__ p0,
                          bf16_t* __restrict__ X0)
{
    int idx = blockIdx.x * 256 + threadIdx.x;
    if (idx >= HP * HP * 64) return;
    int c   = idx & 63;
    int pix = idx >> 6;
    int py = pix / HP, px = pix - py * HP;
    float v = 0.f;
    if (py >= 1 && py <= 512 && px >= 1 && px <= 512) {
        float a = A[(py - 1) * 512 + (px - 1)];
        v = fmaf(w0[c], a, b0[c]);
        v = v >= 0.f ? v : p0[0] * v;
    }
    X0[idx] = f2bf(v);
}

// ---------- zero full rows [r0, r0+n) of a strip buffer ----------
__global__ void zero_rows_kernel(bf16_t* __restrict__ buf, int C, int r0, int n)
{
    int idx = blockIdx.x * 256 + threadIdx.x;
    int rowsz = HP * C;
    if (idx >= n * rowsz) return;
    int r = idx / rowsz, j = idx - r * rowsz;
    buf[(size_t)(r0 + r) * rowsz + j] = f2bf(0.f);
}

// ---------- zero cols 0 and 513 for rows [0, R) ----------
__global__ void zero_cols_kernel(bf16_t* __restrict__ buf, int C, int R)
{
    int idx = blockIdx.x * 256 + threadIdx.x;
    if (idx >= R * 2 * C) return;
    int r = idx / (2 * C);
    int t = idx - r * 2 * C;
    int col = (t < C) ? 0 : 513;
    int c = t % C;
    buf[((size_t)r * HP + col) * C + c] = f2bf(0.f);
}

// ---------- weight transform: OIHW fp32 -> MFMA-fragment-ordered bf16 ----------
// wt[(((ci*9 + tap)*G + gabs)*64 + l)*8 + j] = w[(cout*CIN+cin)*9 + tap]
//   cout = gabs*16 + (l&15), cin = ci*32 + (l>>4)*8 + j, G = COUT/16
// (correctness verified in R3/R4 runs)
__global__ void wtrans_kernel(const float* __restrict__ w, bf16_t* __restrict__ wt,
                              int COUT, int CIN)
{
    int idx = blockIdx.x * 256 + threadIdx.x;
    if (idx >= COUT * CIN * 9) return;
    int G    = COUT / 16;
    int j    = idx & 7;
    int l    = (idx >> 3) & 63;
    int t    = idx >> 9;
    int gabs = t % G;
    int t2   = t / G;
    int tap  = t2 % 9;
    int ci   = t2 / 9;
    int cout = gabs * 16 + (l & 15);
    int cin  = ci * 32 + (l >> 4) * 8 + j;
    wt[idx] = f2bf(w[(cout * CIN + cin) * 9 + tap]);
}

// ---------- 3x3 conv + bias + PReLU, implicit GEMM, bf16 MFMA ----------
// R2 skeleton: block 128 px (16y x 8x) x BN couts, 4 waves (2m x 2n),
// wave tile 4 m-frags x NT B-frags, 1 barrier per tap, A dbuf per 32-ch chunk.
// NEW vs R2: (a) B tiles fragment-ordered -> contiguous conflict-free reads,
// (b) A slab bank-swizzled: unit16(r,px,q) = r*40 + px*4 + ((q+(px>>1))&3)
//     -> each quad-group's ds_read_b128 hits 8 distinct superbanks (2-way = free).
template<int CIN, int COUT, int BN>
__global__ __launch_bounds__(256, 2)
void conv3x3_kernel(const bf16_t* __restrict__ in, const bf16_t* __restrict__ wt,
                    const float* __restrict__ bias, const float* __restrict__ alpha,
                    bf16_t* __restrict__ out,
                    int n_rows, int in_off, int in_alloc, int out_off)
{
    constexpr int G      = COUT / 16;     // global cout groups (wt layout)
    constexpr int GPB    = BN / 16;       // cout groups per block (8 or 4)
    constexpr int NT     = BN / 32;       // cout groups per wave
    constexpr int NC     = CIN / 32;      // channel chunks
    constexpr int AUNITS = 18 * 10 * 4;   // 720 16B-units
    constexpr int ASLAB  = AUNITS * 8;    // 5760 elems per A buffer
    constexpr int BSZ    = BN * 32;       // elems per B tap buffer
    __shared__ __align__(16) bf16_t As[2 * ASLAB];
    __shared__ __align__(16) bf16_t Bs[2 * BSZ];

    const int tid  = threadIdx.x;
    const int lane = tid & 63;
    const int wave = tid >> 6;
    const int lm   = lane & 15;
    const int quad = lane >> 4;
    const int wave_m = wave >> 1;
    const int wave_n = wave & 1;

    const int x0 = blockIdx.x * 8;       // input col base (padded coords)
    const int y0 = blockIdx.y * 16;      // local out row base
    const int zb = blockIdx.z;
    const int gb_blk = zb * GPB;

    // ---- A staging maps: 3 passes of 256 units (720 total) ----
    int a_src[3], a_dst[3];
    #pragma unroll
    for (int it = 0; it < 3; ++it) {
        int u  = it * 256 + tid;
        int uu = u < AUNITS ? u : 0;
        int q = uu & 3, px = (uu >> 2) % 10, r = uu / 40;
        int grow = in_off + y0 + r;
        grow = grow < 0 ? 0 : (grow >= in_alloc ? in_alloc - 1 : grow);
        a_src[it] = (grow * HP + x0 + px) * CIN + q * 8;
        a_dst[it] = (r * 40 + px * 4 + ((q + (px >> 1)) & 3)) * 8;
    }

    // ---- fragment read bases (swizzled) ----
    const int pxb = lm & 7, pyb = lm >> 3;
    int sw[3];
    #pragma unroll
    for (int dx = 0; dx < 3; ++dx)
        sw[dx] = ((quad + ((pxb + dx) >> 1)) & 3) * 8;
    int addrA0[4];
    #pragma unroll
    for (int mt = 0; mt < 4; ++mt)
        addrA0[mt] = ((wave_m * 8 + mt * 2 + pyb) * 40 + pxb * 4) * 8;

    auto loadA = [&](int cc, bf16x8* s) {
        #pragma unroll
        for (int it = 0; it < 3; ++it)
            if (it * 256 + tid < AUNITS)
                s[it] = *(const bf16x8*)(in + a_src[it] + cc);
    };
    auto writeA = [&](const bf16x8* s, int abuf) {
        bf16_t* d = As + abuf * ASLAB;
        #pragma unroll
        for (int it = 0; it < 3; ++it)
            if (it * 256 + tid < AUNITS)
                *(bf16x8*)(d + a_dst[it]) = s[it];
    };
    // B: per tap, GPB groups of 1 KB; wave w stages groups w, w+4
    auto stageB = [&](int ci9t, int bbuf) {
        #pragma unroll
        for (int k = 0; k < GPB / 4; ++k) {
            int g = wave + k * 4;
            const bf16_t* src = wt + ((size_t)ci9t * G + gb_blk + g) * 512 + lane * 8;
            bf16_t* dst = Bs + bbuf * BSZ + g * 512;
            __builtin_amdgcn_global_load_lds((AS1 void*)src, (AS3 void*)dst, 16, 0, 0);
        }
    };

    f32x4 acc[4][NT] = {};
    bf16x8 areg[3];

    // prologue: chunk-0 A -> buf0, tap-0 B -> buf0
    loadA(0, areg);
    writeA(areg, 0);
    stageB(0, 0);
    __syncthreads();

    int ab = 0, bb = 0;
    for (int ci = 0; ci < NC; ++ci) {
        const bool more = (ci + 1 < NC);
        #pragma unroll
        for (int tap = 0; tap < 9; ++tap) {
            // prefetch next tap's (or next chunk's tap-0) B tile
            if (tap < 8)      stageB(ci * 9 + tap + 1, bb ^ 1);
            else if (more)    stageB((ci + 1) * 9, bb ^ 1);
            // prefetch next chunk's A into registers early
            if (tap == 0 && more) loadA((ci + 1) * 32, areg);

            const int dy = tap / 3, dx = tap - dy * 3;
            const int shift = (dy * 40 + dx * 4) * 8 + sw[dx];
            bf16x8 a[4], b[NT];
            #pragma unroll
            for (int nt = 0; nt < NT; ++nt)
                b[nt] = *(const bf16x8*)(Bs + bb * BSZ + (wave_n * NT + nt) * 512 + lane * 8);
            #pragma unroll
            for (int mt = 0; mt < 4; ++mt)
                a[mt] = *(const bf16x8*)(As + ab * ASLAB + addrA0[mt] + shift);
            #pragma unroll
            for (int mt = 0; mt < 4; ++mt)
                #pragma unroll
                for (int nt = 0; nt < NT; ++nt)
                    acc[mt][nt] = __builtin_amdgcn_mfma_f32_16x16x32_bf16(
                        a[mt], b[nt], acc[mt][nt], 0, 0, 0);

            if (tap == 8 && more) writeA(areg, ab ^ 1);
            __syncthreads();
            bb ^= 1;
        }
        ab ^= 1;
    }

    // ---- epilogue: bias + PReLU, bf16 NHWC store (R2-verified mapping) ----
    const float al = alpha[0];
    #pragma unroll
    for (int nt = 0; nt < NT; ++nt) {
        const int n = zb * BN + wave_n * (BN / 2) + nt * 16 + lm;
        const float bv = bias[n];
        #pragma unroll
        for (int mt = 0; mt < 4; ++mt) {
            f32x4 v = acc[mt][nt];
            #pragma unroll
            for (int r = 0; r < 4; ++r) {
                int m  = wave_m * 64 + mt * 16 + quad * 4 + r;
                int py = m >> 3, px = m & 7;
                int ly = y0 + py;
                if (ly < n_rows) {
                    float f = v[r] + bv;
                    f = f >= 0.f ? f : al * f;
                    out[((size_t)(out_off + ly) * HP + (x0 + px + 1)) * COUT + n] = f2bf(f);
                }
            }
        }
    }
}

// ---------- L5 (64->1, k3) + bias + PReLU per strip, fp32 T out ----------
__device__ __forceinline__ float conv64_at(const bf16_t* __restrict__ X,
                                           const float* __restrict__ wsh,
                                           int y, int x, float bv)
{
    float acc = bv;
    #pragma unroll
    for (int dy = 0; dy < 3; ++dy) {
        #pragma unroll
        for (int dx = 0; dx < 3; ++dx) {
            const bf16x8* p = (const bf16x8*)(X + ((size_t)(y + dy) * HP + (x + dx)) * 64);
            const float* wf = wsh + (dy * 3 + dx) * 64;
            #pragma unroll
            for (int j = 0; j < 8; ++j) {
                bf16x8 v = p[j];
                #pragma unroll
                for (int k = 0; k < 8; ++k)
                    acc = fmaf((float)v[k], wf[j * 8 + k], acc);
            }
        }
    }
    return acc;
}

__global__ __launch_bounds__(256)
void l5_strip_kernel(const bf16_t* __restrict__ B4, const bf16_t* __restrict__ wt5,
                     const float* __restrict__ b5, const float* __restrict__ p5,
                     float* __restrict__ T, int abs_row0)
{
    __shared__ float wsh[9 * 64];
    for (int i = threadIdx.x; i < 576; i += 256) wsh[i] = (float)wt5[i];
    __syncthreads();
    int idx = blockIdx.x * 256 + threadIdx.x;
    int ly = idx >> 9, x = idx & 511;
    float bv = b5[0], al = p5[0];
    float t = conv64_at(B4, wsh, ly, x, bv);
    t = t >= 0.f ? t : al * t;
    T[(size_t)(abs_row0 + ly) * 512 + x] = t;
}

// ---------- weight transform for L5 (plain [tap][cin], tiny) ----------
__global__ void wtrans5_kernel(const float* __restrict__ w, bf16_t* __restrict__ wt)
{
    int idx = blockIdx.x * 256 + threadIdx.x;
    if (idx >= 9 * 64) return;
    int cin = idx % 64, tap = idx / 64;
    wt[idx] = f2bf(w[cin * 9 + tap]);
}

// ---------- final symmetrize ----------
__global__ __launch_bounds__(256)
void sym_kernel(const float* __restrict__ T, float* __restrict__ out)
{
    int idx = blockIdx.x * 256 + threadIdx.x;
    int y = idx >> 9, x = idx & 511;
    out[idx] = 0.5f * (T[idx] + T[x * 512 + y]);
}

// ----------------------------------------------------------------------------
extern "C" void kernel_launch(void* const* d_in, const int* in_sizes, int n_in,
                              void* d_out, int out_size, void* d_ws, size_t ws_size,
                              hipStream_t stream)
{
    const float* A = (const float*)d_in[0];
    const float *w[6], *b[6], *p[6];
    for (int i = 0; i < 6; ++i) {
        w[i] = (const float*)d_in[1 + 3 * i];
        b[i] = (const float*)d_in[2 + 3 * i];
        p[i] = (const float*)d_in[3 + 3 * i];
    }

    auto footprint = [](long long S) -> size_t {
        auto al = [](size_t v) { return (v + 255) & ~(size_t)255; };
        size_t t = 0;
        t += al((size_t)HP * HP * 64 * 2);
        t += al((size_t)(S + 8) * HP * 256 * 2);
        t += al((size_t)(S + 6) * HP * 512 * 2);
        t += al((size_t)(S + 2) * HP * 64 * 2);
        t += al((size_t)512 * 512 * 4);
        t += al((size_t)9 * 256 * 64 * 2);
        t += al((size_t)9 * 512 * 256 * 2);
        t += al((size_t)9 * 256 * 512 * 2);
        t += al((size_t)9 * 64 * 256 * 2);
        t += al((size_t)9 * 64 * 2);
        return t;
    };
    const int cand[6] = {512, 256, 128, 64, 32, 16};
    int S = 16;
    for (int i = 0; i < 6; ++i)
        if (footprint(cand[i]) <= ws_size) { S = cand[i]; break; }
    const int nStrips = 512 / S;

    char* ws = (char*)d_ws;
    size_t off = 0;
    auto carve = [&](size_t bytes) -> void* {
        void* r = ws + off;
        off += (bytes + 255) & ~(size_t)255;
        return r;
    };
    bf16_t* X0  = (bf16_t*)carve((size_t)HP * HP * 64 * 2);
    bf16_t* B1  = (bf16_t*)carve((size_t)(S + 8) * HP * 256 * 2);
    bf16_t* B2  = (bf16_t*)carve((size_t)(S + 6) * HP * 512 * 2);
    bf16_t* B4  = (bf16_t*)carve((size_t)(S + 2) * HP * 64 * 2);
    float*  T   = (float*)carve((size_t)512 * 512 * 4);
    bf16_t* wt1 = (bf16_t*)carve((size_t)9 * 256 * 64 * 2);
    bf16_t* wt2 = (bf16_t*)carve((size_t)9 * 512 * 256 * 2);
    bf16_t* wt3 = (bf16_t*)carve((size_t)9 * 256 * 512 * 2);
    bf16_t* wt4 = (bf16_t*)carve((size_t)9 * 64 * 256 * 2);
    bf16_t* wt5 = (bf16_t*)carve((size_t)9 * 64 * 2);
    bf16_t* B3  = B1;   // alias: B1 dead after each strip's L2

    auto cdiv = [](int a, int bq) { return (a + bq - 1) / bq; };
    auto zrows = [&](bf16_t* buf, int C, int r0, int n) {
        if (n > 0)
            zero_rows_kernel<<<cdiv(n * HP * C, 256), 256, 0, stream>>>(buf, C, r0, n);
    };

    wtrans_kernel<<<cdiv(9 * 256 * 64, 256), 256, 0, stream>>>(w[1], wt1, 256, 64);
    wtrans_kernel<<<cdiv(9 * 512 * 256, 256), 256, 0, stream>>>(w[2], wt2, 512, 256);
    wtrans_kernel<<<cdiv(9 * 256 * 512, 256), 256, 0, stream>>>(w[3], wt3, 256, 512);
    wtrans_kernel<<<cdiv(9 * 64 * 256, 256), 256, 0, stream>>>(w[4], wt4, 64, 256);
    wtrans5_kernel<<<cdiv(9 * 64, 256), 256, 0, stream>>>(w[5], wt5);
    l0_kernel<<<cdiv(HP * HP * 64, 256), 256, 0, stream>>>(A, w[0], b[0], p[0], X0);
    zero_cols_kernel<<<cdiv((S + 8) * 2 * 256, 256), 256, 0, stream>>>(B1, 256, S + 8);
    zero_cols_kernel<<<cdiv((S + 6) * 2 * 512, 256), 256, 0, stream>>>(B2, 512, S + 6);
    zero_cols_kernel<<<cdiv((S + 2) * 2 * 64, 256), 256, 0, stream>>>(B4, 64, S + 2);

    for (int s = 0; s < nStrips; ++s) {
        const int base = S * s;
        int o0[5], nn[5], ooff[5], alloc[5];
        for (int k = 1; k <= 4; ++k) {
            int hk = 5 - k;                      // halos 4,3,2,1
            int a0 = base - hk, a1 = base + S + hk;
            int c0 = a0 < 0 ? 0 : a0, c1 = a1 > 512 ? 512 : a1;
            o0[k] = c0; nn[k] = c1 - c0; ooff[k] = c0 - a0; alloc[k] = S + 2 * hk;
        }
        // L1: X0 -> B1
        {
            int in_off = o0[1];
            dim3 g(64, cdiv(nn[1], 16), 2);
            conv3x3_kernel<64, 256, 128><<<g, 256, 0, stream>>>(
                X0, wt1, b[1], p[1], B1, nn[1], in_off, 514, ooff[1]);
            zrows(B1, 256, 0, ooff[1]);
            zrows(B1, 256, ooff[1] + nn[1], alloc[1] - ooff[1] - nn[1]);
        }
        // L2: B1 -> B2
        {
            int in_off = (o0[2] - 1) - (base - 4);
            dim3 g(64, cdiv(nn[2], 16), 4);
            conv3x3_kernel<256, 512, 128><<<g, 256, 0, stream>>>(
                B1, wt2, b[2], p[2], B2, nn[2], in_off, alloc[1], ooff[2]);
            zrows(B2, 512, 0, ooff[2]);
            zrows(B2, 512, ooff[2] + nn[2], alloc[2] - ooff[2] - nn[2]);
        }
        // L3: B2 -> B3
        {
            int in_off = (o0[3] - 1) - (base - 3);
            dim3 g(64, cdiv(nn[3], 16), 2);
            conv3x3_kernel<512, 256, 128><<<g, 256, 0, stream>>>(
                B2, wt3, b[3], p[3], B3, nn[3], in_off, alloc[2], ooff[3]);
            zrows(B3, 256, 0, ooff[3]);
            zrows(B3, 256, ooff[3] + nn[3], alloc[3] - ooff[3] - nn[3]);
        }
        // L4: B3 -> B4
        {
            int in_off = (o0[4] - 1) - (base - 2);
            dim3 g(64, cdiv(nn[4], 16), 1);
            conv3x3_kernel<256, 64, 64><<<g, 256, 0, stream>>>(
                B3, wt4, b[4], p[4], B4, nn[4], in_off, alloc[3], ooff[4]);
            zrows(B4, 64, 0, ooff[4]);
            zrows(B4, 64, ooff[4] + nn[4], alloc[4] - ooff[4] - nn[4]);
        }
        // L5
        l5_strip_kernel<<<(S * 512) / 256, 256, 0, stream>>>(B4, wt5, b[5], p[5], T, base);
    }

    sym_kernel<<<(512 * 512) / 256, 256, 0, stream>>>(T, (float*)d_out);
}